// Round 16
// baseline (229.953 us; speedup 1.0000x reference)
//
#include <hip/hip_runtime.h>
#include <hip/hip_fp16.h>

// ContinuousFilterConv on MI355X (gfx950), round 16.
// filtered[e,i] = sum_{u,j} h[e,u] * tm[e,j] * W2ext[u, i*128+j]
// kpre unchanged (round 15). Round 16: k2+k4+k3 fused into ONE kernel (k2f)
// with a software grid barrier (512 blocks, launch_bounds(256,2) -> 2/CU
// guaranteed co-resident; device-scope atomic counter + release/acquire,
// same pattern as ROCm cooperative-groups grid.sync). Phases:
//   A: outer-product GEMM -> fp partials (round-8 loop, unchanged)
//   B: per-edge 8-partial reduce + scatter-add (1M atomics)
//   C: out = silu(out)
// Counter reset by kpre every call -> graph-replay deterministic.

typedef _Float16 f16;
typedef __attribute__((ext_vector_type(8))) f16 f16x8;
typedef __attribute__((ext_vector_type(4))) float f32x4;
typedef __attribute__((ext_vector_type(4))) unsigned int u32x4;

#define NEDGE 8192
#define NNODE 20000
#define NG    50
#define KSTEPS 516                        // 129 u-rows * 128 j / 32
#define W2C_BYTES (KSTEPS * 8192)         // [step][nt8][lane64][8] f16
#define HT_BYTES (64 * 132 * 128 * 2)     // [eb][u(132, 128=ones)][el(128)] f16
#define TM_BYTES (NEDGE * 128 * 2)        // [e][j^swz] f16 (mask folded, pre-swizzled)
#define CNT_BYTES 256                     // grid-barrier counter (aligned pad)
#define FP_BYTES ((size_t)NEDGE * 8 * 128 * 4)  // f32 partials [e][c][i] = 32 MB

// k2 LDS map (bytes)
#define LDS_H   0                         // 20 rows x 256 B = 5120
#define LDS_TM  5120                      // 128 x 256 B (swizzled) = 32768
#define LDS_TOT 37888

// kpre edge-path LDS map (bytes)
#define K_SRC 0                           // [64e][128u] f16 swz = 16384
#define K_DF  16384                       // [64e][64g]  f16 swz = 8192
#define K_MSK 24576                       // mask f32 [64] = 256
#define K_WTC 24832                       // Wt frags  [s4][nt8][l64][8] = 32768
#define K_W1C 57600                       // W1 frags  [s2][nt8][l64][8] = 16384
#define K_TOT 73984

static __device__ __forceinline__ float fsilu(float x) { return x / (1.0f + __expf(-x)); }

static __device__ __forceinline__ void gll16(const void* g, void* l) {
  __builtin_amdgcn_global_load_lds(
      (const __attribute__((address_space(1))) unsigned int*)g,
      (__attribute__((address_space(3))) unsigned int*)l, 16, 0, 0);
}

// software grid barrier: all blocks co-resident (grid <= min residency).
static __device__ __forceinline__ void gbar(unsigned* cnt, unsigned target) {
  __syncthreads();
  if (threadIdx.x == 0) {
    __threadfence();                                   // release block's writes
    __hip_atomic_fetch_add(cnt, 1u, __ATOMIC_ACQ_REL, __HIP_MEMORY_SCOPE_AGENT);
    while (__hip_atomic_load(cnt, __ATOMIC_ACQUIRE, __HIP_MEMORY_SCOPE_AGENT) < target)
      __builtin_amdgcn_s_sleep(8);
  }
  __syncthreads();
}

// ---- kpre: {W2->w2c (516) | MFMA edge-prep (128, self-converting) | zero} --
__global__ __launch_bounds__(256) void kpre(const float* __restrict__ W2,
                                            const float* __restrict__ b2,
                                            const float* __restrict__ W1,
                                            const float* __restrict__ B1,
                                            const float* __restrict__ WT,
                                            const float* __restrict__ NF,
                                            const int*   __restrict__ EI,
                                            const float* __restrict__ DI,
                                            f16* __restrict__ w2c,
                                            f16* __restrict__ ht2,
                                            f16* __restrict__ tmo,
                                            float* __restrict__ out,
                                            unsigned* __restrict__ cnt, int nz4) {
  __shared__ u32x4 smem_v[K_TOT / 16];
  char* smem = (char*)smem_v;
  const int bid = blockIdx.x, tid = threadIdx.x;

  if (bid < 516) {
    const int u = bid >> 2, s = bid & 3;
    const int i = tid >> 1, half = tid & 1;
    const float* src = ((u < 128) ? (W2 + (size_t)u * 16384) : b2)
                       + i * 128 + s * 32 + half * 16;
    union { f16 s16[16]; u32x4 v[2]; } pk;
#pragma unroll
    for (int q = 0; q < 4; ++q) {
      f32x4 v = *(const f32x4*)(src + q * 4);
#pragma unroll
      for (int r = 0; r < 4; ++r) pk.s16[q * 4 + r] = (f16)v[r];
    }
    const int nt = i >> 4, l15 = i & 15;
    u32x4* dst = (u32x4*)w2c + (size_t)(u * 4 + s) * 512 + nt * 64 + l15;
    dst[(half * 2 + 0) * 16] = pk.v[0];
    dst[(half * 2 + 1) * 16] = pk.v[1];
    return;
  }
  if (bid < 644) {
    const int bid2 = bid - 516;
    const int e0g = bid2 * 64;
    const int eb  = bid2 >> 1;
    const int el0 = (bid2 & 1) * 64;

#pragma unroll
    for (int q = 0; q < 8; ++q) {
      int f = q * 256 + tid;
      int lane = f & 63, nt = (f >> 6) & 7, step = f >> 9;
      int j = nt * 16 + (lane & 15);
      int u0 = step * 32 + (lane >> 4) * 8;
      union { f16 s[8]; u32x4 v; } pk;
#pragma unroll
      for (int r = 0; r < 8; ++r) pk.s[r] = (f16)WT[(u0 + r) * 128 + j];
      *(u32x4*)(smem + K_WTC + f * 16) = pk.v;
    }
#pragma unroll
    for (int q = 0; q < 4; ++q) {
      int f = q * 256 + tid;
      int lane = f & 63, nt = (f >> 6) & 7, step = f >> 9;
      int j = nt * 16 + (lane & 15);
      union { f16 s[8]; u32x4 v; } pk;
#pragma unroll
      for (int r = 0; r < 8; ++r) {
        int g = step * 32 + (lane >> 4) * 8 + r;
        float v = (g < 50) ? W1[g * 128 + j] : ((g == 63) ? B1[j] : 0.0f);
        pk.s[r] = (f16)v;
      }
      *(u32x4*)(smem + K_W1C + f * 16) = pk.v;
    }
    if (tid < 64) {
      float d = DI[e0g + tid];
      *(float*)(smem + K_MSK + tid * 4) = (d <= 8.0f) ? 1.0f : 0.0f;
    }
    {
      int e = tid >> 2, g0 = (tid & 3) * 16;
      float d = DI[e0g + e];
      union { f16 s[16]; u32x4 v[2]; } pk;
#pragma unroll
      for (int gg = 0; gg < 16; ++gg) {
        int g = g0 + gg;
        float x = d - (float)g * (30.0f / 49.0f);
        float v = (g < 50) ? __expf(-10.0f * x * x) : ((g == 63) ? 1.0f : 0.0f);
        pk.s[gg] = (f16)v;
      }
      int base = e * 128 + g0 * 2, sw = (e & 7) << 4;
      *(u32x4*)(smem + K_DF + ((base) ^ sw))      = pk.v[0];
      *(u32x4*)(smem + K_DF + ((base + 16) ^ sw)) = pk.v[1];
    }
#pragma unroll
    for (int p = 0; p < 8; ++p) {
      int e = p * 8 + (tid >> 5);
      int u0 = (tid & 31) * 4;
      int row = EI[e0g + e];
      f32x4 v = *(const f32x4*)(NF + (size_t)row * 128 + u0);
      union { f16 s[4]; unsigned long long q; } pk;
#pragma unroll
      for (int r = 0; r < 4; ++r) pk.s[r] = (f16)v[r];
      int addr = e * 256 + u0 * 2;
      *(unsigned long long*)(smem + K_SRC + (addr ^ ((e & 7) << 4))) = pk.q;
    }
    __syncthreads();

    const int w = tid >> 6, lane = tid & 63;
    const int l15 = lane & 15, g4 = lane >> 4;
    const int erow = w * 16;
    const int asw = (l15 & 7) << 4;

    f32x4 at[8], ah[8];
#pragma unroll
    for (int nt = 0; nt < 8; ++nt) {
      at[nt] = (f32x4){0.f, 0.f, 0.f, 0.f};
      ah[nt] = (f32x4){0.f, 0.f, 0.f, 0.f};
    }
#pragma unroll
    for (int step = 0; step < 4; ++step) {
      int aaddr = (erow + l15) * 256 + step * 64 + g4 * 16;
      f16x8 a = *(const f16x8*)(smem + K_SRC + (aaddr ^ asw));
#pragma unroll
      for (int nt = 0; nt < 8; ++nt) {
        f16x8 b = *(const f16x8*)(smem + K_WTC + ((step * 8 + nt) * 64 + lane) * 16);
        at[nt] = __builtin_amdgcn_mfma_f32_16x16x32_f16(a, b, at[nt], 0, 0, 0);
      }
    }
#pragma unroll
    for (int step = 0; step < 2; ++step) {
      int aaddr = (erow + l15) * 128 + step * 64 + g4 * 16;
      f16x8 a = *(const f16x8*)(smem + K_DF + (aaddr ^ asw));
#pragma unroll
      for (int nt = 0; nt < 8; ++nt) {
        f16x8 b = *(const f16x8*)(smem + K_W1C + ((step * 8 + nt) * 64 + lane) * 16);
        ah[nt] = __builtin_amdgcn_mfma_f32_16x16x32_f16(a, b, ah[nt], 0, 0, 0);
      }
    }
    const float* mk = (const float*)(smem + K_MSK);
#pragma unroll
    for (int r = 0; r < 4; ++r) {
      int el_ = erow + g4 * 4 + r;
      float m = mk[el_];
      int sw2 = (el_ & 7) << 4;
      char* rowp = (char*)tmo + (size_t)(e0g + el_) * 256;
#pragma unroll
      for (int nt = 0; nt < 8; ++nt)
        *(f16*)(rowp + (((nt * 16 + l15) * 2) ^ sw2)) = (f16)(m * at[nt][r]);
    }
#pragma unroll
    for (int r = 0; r < 4; ++r) {
      int el_ = el0 + erow + g4 * 4 + r;
#pragma unroll
      for (int nt = 0; nt < 8; ++nt) {
        int u = nt * 16 + l15;
        ht2[((size_t)eb * 132 + u) * 128 + el_] = (f16)fsilu(ah[nt][r]);
      }
    }
    if (tid < 64) ht2[((size_t)eb * 132 + 128) * 128 + el0 + tid] = (f16)1.0f;
    return;
  }
  // ---- zero d_out (+ reset grid-barrier counter) ----
  {
    if (bid == 644 && tid == 0) *cnt = 0u;
    int base = (bid - 644) * 1024;
    f32x4 z = {0.f, 0.f, 0.f, 0.f};
#pragma unroll
    for (int k = 0; k < 4; ++k) {
      int i4 = base + k * 256 + tid;
      if (i4 < nz4) ((f32x4*)out)[i4] = z;
    }
  }
}

// ---- k2f: fused {GEMM -> partials | grid-bar | reduce+scatter | grid-bar |
//                  silu}. 512 blocks, launch_bounds(256,2) -> co-resident. ---
// MODE 0: fp path. MODE 1 (small ws): atomic epilogue, then barrier + silu.
template<int MODE>
__global__ __launch_bounds__(256, 2) void k2f(const f16* __restrict__ w2c,
                                              const f16* __restrict__ ht2,
                                              const f16* __restrict__ tm,
                                              const int* __restrict__ EI,
                                              float* __restrict__ fpart,
                                              float* __restrict__ out,
                                              unsigned* __restrict__ cnt, int nz4) {
  __shared__ u32x4 smem_v[LDS_TOT / 16];
  char* smem = (char*)smem_v;

  const int bid = blockIdx.x;
  const int c   = bid & 7;
  const int eb  = bid >> 3;
  const int e0  = eb * 128;
  const int nu  = (c == 7) ? 17 : 16;
  const int tid = threadIdx.x, w = tid >> 6, lane = tid & 63;
  const int l15 = lane & 15, g4 = lane >> 4;
  const int wm = w >> 1, wn = w & 1;

  // ---- phase A: GEMM (round-8 loop, B-first prologue) ----
  const char* bp = (const char*)w2c + (size_t)(c * 64) * 8192 + wn * 4096 + lane * 16;
  f16x8 B0[4], B1[4];
#pragma unroll
  for (int nt = 0; nt < 4; ++nt) B0[nt] = *(const f16x8*)(bp + nt * 1024);
#pragma unroll
  for (int nt = 0; nt < 4; ++nt) B1[nt] = *(const f16x8*)(bp + 8192 + nt * 1024);

  {
    const char* tsrc = (const char*)tm + (size_t)e0 * 256 + w * 8192;
#pragma unroll
    for (int q = 0; q < 8; ++q)
      gll16(tsrc + q * 1024 + lane * 16,
            smem + LDS_TM + w * 8192 + q * 1024 + lane * 16);
  }
  if (w == 0) {   // 20 h rows
    const char* hsrc = (const char*)ht2 + ((size_t)eb * 132 + c * 16) * 256;
#pragma unroll
    for (int q = 0; q < 5; ++q)
      gll16(hsrc + q * 1024 + lane * 16, smem + LDS_H + q * 1024 + lane * 16);
  }
  __syncthreads();

  f16x8 Tall[4][4];
  {
    const int tmrow = LDS_TM + (wm * 64 + l15) * 256;
    const int colsw = (l15 & 7) << 4;
#pragma unroll
    for (int rt = 0; rt < 4; ++rt)
#pragma unroll
      for (int jc = 0; jc < 4; ++jc)
        Tall[rt][jc] = *(const f16x8*)(smem + tmrow + rt * 4096 +
                                       ((jc * 64 + g4 * 16) ^ colsw));
  }
  const __half* hbase = (const __half*)(smem + LDS_H) + wm * 64 + l15;

  __half2 hc[4], hn[4];
#pragma unroll
  for (int rt = 0; rt < 4; ++rt) hc[rt] = __half2half2(hbase[rt * 16]);

  size_t off = 2 * 8192;
  f32x4 acc[4][4];
#pragma unroll
  for (int rt = 0; rt < 4; ++rt)
#pragma unroll
    for (int nt = 0; nt < 4; ++nt) acc[rt][nt] = (f32x4){0.f, 0.f, 0.f, 0.f};

  for (int u = 0; u < nu; ++u) {
#pragma unroll
    for (int jc = 0; jc < 4; ++jc) {
      if (jc == 1) {
#pragma unroll
        for (int rt = 0; rt < 4; ++rt)
          hn[rt] = __half2half2(hbase[(u + 1) * 128 + rt * 16]);
      }
      union uf { f16x8 v; __half2 h[4]; };
      uf a[4];
#pragma unroll
      for (int rt = 0; rt < 4; ++rt) {
        uf t; t.v = Tall[rt][jc];
#pragma unroll
        for (int q = 0; q < 4; ++q) a[rt].h[q] = __hmul2(t.h[q], hc[rt]);
      }
      __builtin_amdgcn_s_setprio(1);
#pragma unroll
      for (int nt = 0; nt < 4; ++nt) {
        if ((jc & 1) == 0) {
#pragma unroll
          for (int rt = 0; rt < 4; ++rt)
            acc[rt][nt] = __builtin_amdgcn_mfma_f32_16x16x32_f16(a[rt].v, B0[nt], acc[rt][nt], 0, 0, 0);
          B0[nt] = *(const f16x8*)(bp + off + nt * 1024);
        } else {
#pragma unroll
          for (int rt = 0; rt < 4; ++rt)
            acc[rt][nt] = __builtin_amdgcn_mfma_f32_16x16x32_f16(a[rt].v, B1[nt], acc[rt][nt], 0, 0, 0);
          B1[nt] = *(const f16x8*)(bp + off + nt * 1024);
        }
      }
      __builtin_amdgcn_s_setprio(0);
      off += 8192;
    }
#pragma unroll
    for (int rt = 0; rt < 4; ++rt) hc[rt] = hn[rt];
  }

  if (MODE == 0) {
#pragma unroll
    for (int rt = 0; rt < 4; ++rt) {
#pragma unroll
      for (int r = 0; r < 4; ++r) {
        int e = e0 + wm * 64 + rt * 16 + g4 * 4 + r;
        float* prow = fpart + ((size_t)e * 8 + c) * 128 + wn * 64 + l15;
#pragma unroll
        for (int nt = 0; nt < 4; ++nt)
          prow[nt * 16] = acc[rt][nt][r];
      }
    }
  } else {
    const int* dst = EI + NEDGE;
#pragma unroll
    for (int rt = 0; rt < 4; ++rt) {
#pragma unroll
      for (int r = 0; r < 4; ++r) {
        int e = e0 + wm * 64 + rt * 16 + g4 * 4 + r;
        float* row = out + (size_t)dst[e] * 128 + wn * 64 + l15;
#pragma unroll
        for (int nt = 0; nt < 4; ++nt)
          atomicAdd(row + nt * 16, acc[rt][nt][r]);
      }
    }
  }

  // ---- phase B: per-edge reduce + scatter (MODE 0 only) ----
  if (MODE == 0) {
    gbar(cnt, 512);
    const int* dst = EI + NEDGE;
#pragma unroll
    for (int it = 0; it < 2; ++it) {
      int gid = it * 131072 + bid * 256 + tid;    // 262144 = 8192e x 32
      int e  = gid >> 5;
      int i0 = (gid & 31) << 2;
      const float* ep = fpart + (size_t)e * 1024 + i0;
      f32x4 s = {0.f, 0.f, 0.f, 0.f};
#pragma unroll
      for (int cc = 0; cc < 8; ++cc) {
        f32x4 v = *(const f32x4*)(ep + cc * 128);
        s[0] += v[0]; s[1] += v[1]; s[2] += v[2]; s[3] += v[3];
      }
      float* row = out + (size_t)dst[e] * 128 + i0;
      atomicAdd(row + 0, s[0]);
      atomicAdd(row + 1, s[1]);
      atomicAdd(row + 2, s[2]);
      atomicAdd(row + 3, s[3]);
    }
    gbar(cnt, 1024);
  } else {
    gbar(cnt, 512);
  }

  // ---- phase C: out = silu(out) ----
  {
    int idx = bid * 256 + tid;
    f32x4* p = (f32x4*)out;
    for (; idx < nz4; idx += 512 * 256) {
      f32x4 v = p[idx];
#pragma unroll
      for (int cc = 0; cc < 4; ++cc) v[cc] = fsilu(v[cc]);
      p[idx] = v;
    }
  }
}

extern "C" void kernel_launch(void* const* d_in, const int* in_sizes, int n_in,
                              void* d_out, int out_size, void* d_ws, size_t ws_size,
                              hipStream_t stream) {
  const float* NF = (const float*)d_in[0];
  const int*   EI = (const int*)  d_in[1];
  const float* DI = (const float*)d_in[2];
  const float* W1 = (const float*)d_in[3];
  const float* B1 = (const float*)d_in[4];
  const float* W2 = (const float*)d_in[5];
  const float* B2 = (const float*)d_in[6];
  const float* WT = (const float*)d_in[7];
  float* out = (float*)d_out;

  char* base = (char*)d_ws;
  f16*      w2c = (f16*)base;
  f16*      ht2 = (f16*)(base + W2C_BYTES);
  f16*      tmo = (f16*)(base + W2C_BYTES + HT_BYTES);
  unsigned* cnt = (unsigned*)(base + W2C_BYTES + HT_BYTES + TM_BYTES);
  float*    fp  = (float*)(base + W2C_BYTES + HT_BYTES + TM_BYTES + CNT_BYTES);
  size_t need_min  = (size_t)W2C_BYTES + HT_BYTES + TM_BYTES + CNT_BYTES;
  size_t need_fast = need_min + FP_BYTES;
  if (ws_size < need_min) return;  // insufficient scratch: fail loudly
  const bool fast = (ws_size >= need_fast);

  int nz4 = out_size / 4;
  int zb  = (nz4 + 1023) / 1024;
  kpre<<<dim3(644 + zb), dim3(256), 0, stream>>>(W2, B2, W1, B1, WT, NF, EI, DI,
                                                 w2c, ht2, tmo, out, cnt, nz4);
  if (fast) {
    k2f<0><<<dim3(512), dim3(256), 0, stream>>>(w2c, ht2, tmo, EI, fp, out, cnt, nz4);
  } else {
    k2f<1><<<dim3(512), dim3(256), 0, stream>>>(w2c, ht2, tmo, EI, fp, out, cnt, nz4);
  }
}

// Round 17
// 178.485 us; speedup vs baseline: 1.2884x; 1.2884x over previous
//
#include <hip/hip_runtime.h>
#include <hip/hip_fp16.h>

// ContinuousFilterConv on MI355X (gfx950), round 17.
// Same structure as round 16 (kpre; fused k2f = GEMM | grid-bar | reduce+
// scatter | grid-bar | silu). FIX: round 16's grid barrier spun on an
// AGENT-scope ACQUIRE load -> gfx950 emits an L2-invalidate per poll ->
// machine-wide L2 invalidation storm (FETCH 12->33MB, MfmaUtil 25->6%).
// Now: release fence + RELAXED arrive, RELAXED spin, ONE acquire fence on
// exit (cooperative-groups pattern).

typedef _Float16 f16;
typedef __attribute__((ext_vector_type(8))) f16 f16x8;
typedef __attribute__((ext_vector_type(4))) float f32x4;
typedef __attribute__((ext_vector_type(4))) unsigned int u32x4;

#define NEDGE 8192
#define NNODE 20000
#define NG    50
#define KSTEPS 516                        // 129 u-rows * 128 j / 32
#define W2C_BYTES (KSTEPS * 8192)         // [step][nt8][lane64][8] f16
#define HT_BYTES (64 * 132 * 128 * 2)     // [eb][u(132, 128=ones)][el(128)] f16
#define TM_BYTES (NEDGE * 128 * 2)        // [e][j^swz] f16 (mask folded, pre-swizzled)
#define CNT_BYTES 256                     // grid-barrier counter (aligned pad)
#define FP_BYTES ((size_t)NEDGE * 8 * 128 * 4)  // f32 partials [e][c][i] = 32 MB

// k2 LDS map (bytes)
#define LDS_H   0                         // 20 rows x 256 B = 5120
#define LDS_TM  5120                      // 128 x 256 B (swizzled) = 32768
#define LDS_TOT 37888

// kpre edge-path LDS map (bytes)
#define K_SRC 0                           // [64e][128u] f16 swz = 16384
#define K_DF  16384                       // [64e][64g]  f16 swz = 8192
#define K_MSK 24576                       // mask f32 [64] = 256
#define K_WTC 24832                       // Wt frags  [s4][nt8][l64][8] = 32768
#define K_W1C 57600                       // W1 frags  [s2][nt8][l64][8] = 16384
#define K_TOT 73984

static __device__ __forceinline__ float fsilu(float x) { return x / (1.0f + __expf(-x)); }

static __device__ __forceinline__ void gll16(const void* g, void* l) {
  __builtin_amdgcn_global_load_lds(
      (const __attribute__((address_space(1))) unsigned int*)g,
      (__attribute__((address_space(3))) unsigned int*)l, 16, 0, 0);
}

// software grid barrier (all blocks co-resident). Release fence + RELAXED
// arrive; RELAXED spin (no per-poll L2 invalidate!); ONE acquire fence on exit.
static __device__ __forceinline__ void gbar(unsigned* cnt, unsigned target) {
  __syncthreads();
  if (threadIdx.x == 0) {
    __threadfence();                                   // agent release: L2 WB
    __hip_atomic_fetch_add(cnt, 1u, __ATOMIC_RELAXED, __HIP_MEMORY_SCOPE_AGENT);
    while (__hip_atomic_load(cnt, __ATOMIC_RELAXED, __HIP_MEMORY_SCOPE_AGENT) < target)
      __builtin_amdgcn_s_sleep(64);
    __builtin_amdgcn_fence(__ATOMIC_ACQUIRE, "agent"); // one L2 INV on exit
  }
  __syncthreads();
}

// ---- kpre: {W2->w2c (516) | MFMA edge-prep (128, self-converting) | zero} --
__global__ __launch_bounds__(256) void kpre(const float* __restrict__ W2,
                                            const float* __restrict__ b2,
                                            const float* __restrict__ W1,
                                            const float* __restrict__ B1,
                                            const float* __restrict__ WT,
                                            const float* __restrict__ NF,
                                            const int*   __restrict__ EI,
                                            const float* __restrict__ DI,
                                            f16* __restrict__ w2c,
                                            f16* __restrict__ ht2,
                                            f16* __restrict__ tmo,
                                            float* __restrict__ out,
                                            unsigned* __restrict__ cnt, int nz4) {
  __shared__ u32x4 smem_v[K_TOT / 16];
  char* smem = (char*)smem_v;
  const int bid = blockIdx.x, tid = threadIdx.x;

  if (bid < 516) {
    const int u = bid >> 2, s = bid & 3;
    const int i = tid >> 1, half = tid & 1;
    const float* src = ((u < 128) ? (W2 + (size_t)u * 16384) : b2)
                       + i * 128 + s * 32 + half * 16;
    union { f16 s16[16]; u32x4 v[2]; } pk;
#pragma unroll
    for (int q = 0; q < 4; ++q) {
      f32x4 v = *(const f32x4*)(src + q * 4);
#pragma unroll
      for (int r = 0; r < 4; ++r) pk.s16[q * 4 + r] = (f16)v[r];
    }
    const int nt = i >> 4, l15 = i & 15;
    u32x4* dst = (u32x4*)w2c + (size_t)(u * 4 + s) * 512 + nt * 64 + l15;
    dst[(half * 2 + 0) * 16] = pk.v[0];
    dst[(half * 2 + 1) * 16] = pk.v[1];
    return;
  }
  if (bid < 644) {
    const int bid2 = bid - 516;
    const int e0g = bid2 * 64;
    const int eb  = bid2 >> 1;
    const int el0 = (bid2 & 1) * 64;

#pragma unroll
    for (int q = 0; q < 8; ++q) {
      int f = q * 256 + tid;
      int lane = f & 63, nt = (f >> 6) & 7, step = f >> 9;
      int j = nt * 16 + (lane & 15);
      int u0 = step * 32 + (lane >> 4) * 8;
      union { f16 s[8]; u32x4 v; } pk;
#pragma unroll
      for (int r = 0; r < 8; ++r) pk.s[r] = (f16)WT[(u0 + r) * 128 + j];
      *(u32x4*)(smem + K_WTC + f * 16) = pk.v;
    }
#pragma unroll
    for (int q = 0; q < 4; ++q) {
      int f = q * 256 + tid;
      int lane = f & 63, nt = (f >> 6) & 7, step = f >> 9;
      int j = nt * 16 + (lane & 15);
      union { f16 s[8]; u32x4 v; } pk;
#pragma unroll
      for (int r = 0; r < 8; ++r) {
        int g = step * 32 + (lane >> 4) * 8 + r;
        float v = (g < 50) ? W1[g * 128 + j] : ((g == 63) ? B1[j] : 0.0f);
        pk.s[r] = (f16)v;
      }
      *(u32x4*)(smem + K_W1C + f * 16) = pk.v;
    }
    if (tid < 64) {
      float d = DI[e0g + tid];
      *(float*)(smem + K_MSK + tid * 4) = (d <= 8.0f) ? 1.0f : 0.0f;
    }
    {
      int e = tid >> 2, g0 = (tid & 3) * 16;
      float d = DI[e0g + e];
      union { f16 s[16]; u32x4 v[2]; } pk;
#pragma unroll
      for (int gg = 0; gg < 16; ++gg) {
        int g = g0 + gg;
        float x = d - (float)g * (30.0f / 49.0f);
        float v = (g < 50) ? __expf(-10.0f * x * x) : ((g == 63) ? 1.0f : 0.0f);
        pk.s[gg] = (f16)v;
      }
      int base = e * 128 + g0 * 2, sw = (e & 7) << 4;
      *(u32x4*)(smem + K_DF + ((base) ^ sw))      = pk.v[0];
      *(u32x4*)(smem + K_DF + ((base + 16) ^ sw)) = pk.v[1];
    }
#pragma unroll
    for (int p = 0; p < 8; ++p) {
      int e = p * 8 + (tid >> 5);
      int u0 = (tid & 31) * 4;
      int row = EI[e0g + e];
      f32x4 v = *(const f32x4*)(NF + (size_t)row * 128 + u0);
      union { f16 s[4]; unsigned long long q; } pk;
#pragma unroll
      for (int r = 0; r < 4; ++r) pk.s[r] = (f16)v[r];
      int addr = e * 256 + u0 * 2;
      *(unsigned long long*)(smem + K_SRC + (addr ^ ((e & 7) << 4))) = pk.q;
    }
    __syncthreads();

    const int w = tid >> 6, lane = tid & 63;
    const int l15 = lane & 15, g4 = lane >> 4;
    const int erow = w * 16;
    const int asw = (l15 & 7) << 4;

    f32x4 at[8], ah[8];
#pragma unroll
    for (int nt = 0; nt < 8; ++nt) {
      at[nt] = (f32x4){0.f, 0.f, 0.f, 0.f};
      ah[nt] = (f32x4){0.f, 0.f, 0.f, 0.f};
    }
#pragma unroll
    for (int step = 0; step < 4; ++step) {
      int aaddr = (erow + l15) * 256 + step * 64 + g4 * 16;
      f16x8 a = *(const f16x8*)(smem + K_SRC + (aaddr ^ asw));
#pragma unroll
      for (int nt = 0; nt < 8; ++nt) {
        f16x8 b = *(const f16x8*)(smem + K_WTC + ((step * 8 + nt) * 64 + lane) * 16);
        at[nt] = __builtin_amdgcn_mfma_f32_16x16x32_f16(a, b, at[nt], 0, 0, 0);
      }
    }
#pragma unroll
    for (int step = 0; step < 2; ++step) {
      int aaddr = (erow + l15) * 128 + step * 64 + g4 * 16;
      f16x8 a = *(const f16x8*)(smem + K_DF + (aaddr ^ asw));
#pragma unroll
      for (int nt = 0; nt < 8; ++nt) {
        f16x8 b = *(const f16x8*)(smem + K_W1C + ((step * 8 + nt) * 64 + lane) * 16);
        ah[nt] = __builtin_amdgcn_mfma_f32_16x16x32_f16(a, b, ah[nt], 0, 0, 0);
      }
    }
    const float* mk = (const float*)(smem + K_MSK);
#pragma unroll
    for (int r = 0; r < 4; ++r) {
      int el_ = erow + g4 * 4 + r;
      float m = mk[el_];
      int sw2 = (el_ & 7) << 4;
      char* rowp = (char*)tmo + (size_t)(e0g + el_) * 256;
#pragma unroll
      for (int nt = 0; nt < 8; ++nt)
        *(f16*)(rowp + (((nt * 16 + l15) * 2) ^ sw2)) = (f16)(m * at[nt][r]);
    }
#pragma unroll
    for (int r = 0; r < 4; ++r) {
      int el_ = el0 + erow + g4 * 4 + r;
#pragma unroll
      for (int nt = 0; nt < 8; ++nt) {
        int u = nt * 16 + l15;
        ht2[((size_t)eb * 132 + u) * 128 + el_] = (f16)fsilu(ah[nt][r]);
      }
    }
    if (tid < 64) ht2[((size_t)eb * 132 + 128) * 128 + el0 + tid] = (f16)1.0f;
    return;
  }
  // ---- zero d_out (+ reset grid-barrier counter) ----
  {
    if (bid == 644 && tid == 0) *cnt = 0u;
    int base = (bid - 644) * 1024;
    f32x4 z = {0.f, 0.f, 0.f, 0.f};
#pragma unroll
    for (int k = 0; k < 4; ++k) {
      int i4 = base + k * 256 + tid;
      if (i4 < nz4) ((f32x4*)out)[i4] = z;
    }
  }
}

// ---- k2f: fused {GEMM -> partials | grid-bar | reduce+scatter | grid-bar |
//                  silu}. 512 blocks, launch_bounds(256,2) -> co-resident. ---
template<int MODE>
__global__ __launch_bounds__(256, 2) void k2f(const f16* __restrict__ w2c,
                                              const f16* __restrict__ ht2,
                                              const f16* __restrict__ tm,
                                              const int* __restrict__ EI,
                                              float* __restrict__ fpart,
                                              float* __restrict__ out,
                                              unsigned* __restrict__ cnt, int nz4) {
  __shared__ u32x4 smem_v[LDS_TOT / 16];
  char* smem = (char*)smem_v;

  const int bid = blockIdx.x;
  const int c   = bid & 7;
  const int eb  = bid >> 3;
  const int e0  = eb * 128;
  const int nu  = (c == 7) ? 17 : 16;
  const int tid = threadIdx.x, w = tid >> 6, lane = tid & 63;
  const int l15 = lane & 15, g4 = lane >> 4;
  const int wm = w >> 1, wn = w & 1;

  // ---- phase A: GEMM (round-8 loop, B-first prologue) ----
  const char* bp = (const char*)w2c + (size_t)(c * 64) * 8192 + wn * 4096 + lane * 16;
  f16x8 B0[4], B1[4];
#pragma unroll
  for (int nt = 0; nt < 4; ++nt) B0[nt] = *(const f16x8*)(bp + nt * 1024);
#pragma unroll
  for (int nt = 0; nt < 4; ++nt) B1[nt] = *(const f16x8*)(bp + 8192 + nt * 1024);

  {
    const char* tsrc = (const char*)tm + (size_t)e0 * 256 + w * 8192;
#pragma unroll
    for (int q = 0; q < 8; ++q)
      gll16(tsrc + q * 1024 + lane * 16,
            smem + LDS_TM + w * 8192 + q * 1024 + lane * 16);
  }
  if (w == 0) {   // 20 h rows
    const char* hsrc = (const char*)ht2 + ((size_t)eb * 132 + c * 16) * 256;
#pragma unroll
    for (int q = 0; q < 5; ++q)
      gll16(hsrc + q * 1024 + lane * 16, smem + LDS_H + q * 1024 + lane * 16);
  }
  __syncthreads();

  f16x8 Tall[4][4];
  {
    const int tmrow = LDS_TM + (wm * 64 + l15) * 256;
    const int colsw = (l15 & 7) << 4;
#pragma unroll
    for (int rt = 0; rt < 4; ++rt)
#pragma unroll
      for (int jc = 0; jc < 4; ++jc)
        Tall[rt][jc] = *(const f16x8*)(smem + tmrow + rt * 4096 +
                                       ((jc * 64 + g4 * 16) ^ colsw));
  }
  const __half* hbase = (const __half*)(smem + LDS_H) + wm * 64 + l15;

  __half2 hc[4], hn[4];
#pragma unroll
  for (int rt = 0; rt < 4; ++rt) hc[rt] = __half2half2(hbase[rt * 16]);

  size_t off = 2 * 8192;
  f32x4 acc[4][4];
#pragma unroll
  for (int rt = 0; rt < 4; ++rt)
#pragma unroll
    for (int nt = 0; nt < 4; ++nt) acc[rt][nt] = (f32x4){0.f, 0.f, 0.f, 0.f};

  for (int u = 0; u < nu; ++u) {
#pragma unroll
    for (int jc = 0; jc < 4; ++jc) {
      if (jc == 1) {
#pragma unroll
        for (int rt = 0; rt < 4; ++rt)
          hn[rt] = __half2half2(hbase[(u + 1) * 128 + rt * 16]);
      }
      union uf { f16x8 v; __half2 h[4]; };
      uf a[4];
#pragma unroll
      for (int rt = 0; rt < 4; ++rt) {
        uf t; t.v = Tall[rt][jc];
#pragma unroll
        for (int q = 0; q < 4; ++q) a[rt].h[q] = __hmul2(t.h[q], hc[rt]);
      }
      __builtin_amdgcn_s_setprio(1);
#pragma unroll
      for (int nt = 0; nt < 4; ++nt) {
        if ((jc & 1) == 0) {
#pragma unroll
          for (int rt = 0; rt < 4; ++rt)
            acc[rt][nt] = __builtin_amdgcn_mfma_f32_16x16x32_f16(a[rt].v, B0[nt], acc[rt][nt], 0, 0, 0);
          B0[nt] = *(const f16x8*)(bp + off + nt * 1024);
        } else {
#pragma unroll
          for (int rt = 0; rt < 4; ++rt)
            acc[rt][nt] = __builtin_amdgcn_mfma_f32_16x16x32_f16(a[rt].v, B1[nt], acc[rt][nt], 0, 0, 0);
          B1[nt] = *(const f16x8*)(bp + off + nt * 1024);
        }
      }
      __builtin_amdgcn_s_setprio(0);
      off += 8192;
    }
#pragma unroll
    for (int rt = 0; rt < 4; ++rt) hc[rt] = hn[rt];
  }

  if (MODE == 0) {
#pragma unroll
    for (int rt = 0; rt < 4; ++rt) {
#pragma unroll
      for (int r = 0; r < 4; ++r) {
        int e = e0 + wm * 64 + rt * 16 + g4 * 4 + r;
        float* prow = fpart + ((size_t)e * 8 + c) * 128 + wn * 64 + l15;
#pragma unroll
        for (int nt = 0; nt < 4; ++nt)
          prow[nt * 16] = acc[rt][nt][r];
      }
    }
  } else {
    const int* dst = EI + NEDGE;
#pragma unroll
    for (int rt = 0; rt < 4; ++rt) {
#pragma unroll
      for (int r = 0; r < 4; ++r) {
        int e = e0 + wm * 64 + rt * 16 + g4 * 4 + r;
        float* row = out + (size_t)dst[e] * 128 + wn * 64 + l15;
#pragma unroll
        for (int nt = 0; nt < 4; ++nt)
          atomicAdd(row + nt * 16, acc[rt][nt][r]);
      }
    }
  }

  // ---- phase B: per-edge reduce + scatter (MODE 0 only) ----
  if (MODE == 0) {
    gbar(cnt, 512);
    const int* dst = EI + NEDGE;
#pragma unroll
    for (int it = 0; it < 2; ++it) {
      int gid = it * 131072 + bid * 256 + tid;    // 262144 = 8192e x 32
      int e  = gid >> 5;
      int i0 = (gid & 31) << 2;
      const float* ep = fpart + (size_t)e * 1024 + i0;
      f32x4 s = {0.f, 0.f, 0.f, 0.f};
#pragma unroll
      for (int cc = 0; cc < 8; ++cc) {
        f32x4 v = *(const f32x4*)(ep + cc * 128);
        s[0] += v[0]; s[1] += v[1]; s[2] += v[2]; s[3] += v[3];
      }
      float* row = out + (size_t)dst[e] * 128 + i0;
      atomicAdd(row + 0, s[0]);
      atomicAdd(row + 1, s[1]);
      atomicAdd(row + 2, s[2]);
      atomicAdd(row + 3, s[3]);
    }
    gbar(cnt, 1024);
  } else {
    gbar(cnt, 512);
  }

  // ---- phase C: out = silu(out) ----
  {
    int idx = bid * 256 + tid;
    f32x4* p = (f32x4*)out;
    for (; idx < nz4; idx += 512 * 256) {
      f32x4 v = p[idx];
#pragma unroll
      for (int cc = 0; cc < 4; ++cc) v[cc] = fsilu(v[cc]);
      p[idx] = v;
    }
  }
}

extern "C" void kernel_launch(void* const* d_in, const int* in_sizes, int n_in,
                              void* d_out, int out_size, void* d_ws, size_t ws_size,
                              hipStream_t stream) {
  const float* NF = (const float*)d_in[0];
  const int*   EI = (const int*)  d_in[1];
  const float* DI = (const float*)d_in[2];
  const float* W1 = (const float*)d_in[3];
  const float* B1 = (const float*)d_in[4];
  const float* W2 = (const float*)d_in[5];
  const float* B2 = (const float*)d_in[6];
  const float* WT = (const float*)d_in[7];
  float* out = (float*)d_out;

  char* base = (char*)d_ws;
  f16*      w2c = (f16*)base;
  f16*      ht2 = (f16*)(base + W2C_BYTES);
  f16*      tmo = (f16*)(base + W2C_BYTES + HT_BYTES);
  unsigned* cnt = (unsigned*)(base + W2C_BYTES + HT_BYTES + TM_BYTES);
  float*    fp  = (float*)(base + W2C_BYTES + HT_BYTES + TM_BYTES + CNT_BYTES);
  size_t need_min  = (size_t)W2C_BYTES + HT_BYTES + TM_BYTES + CNT_BYTES;
  size_t need_fast = need_min + FP_BYTES;
  if (ws_size < need_min) return;  // insufficient scratch: fail loudly
  const bool fast = (ws_size >= need_fast);

  int nz4 = out_size / 4;
  int zb  = (nz4 + 1023) / 1024;
  kpre<<<dim3(644 + zb), dim3(256), 0, stream>>>(W2, B2, W1, B1, WT, NF, EI, DI,
                                                 w2c, ht2, tmo, out, cnt, nz4);
  if (fast) {
    k2f<0><<<dim3(512), dim3(256), 0, stream>>>(w2c, ht2, tmo, EI, fp, out, cnt, nz4);
  } else {
    k2f<1><<<dim3(512), dim3(256), 0, stream>>>(w2c, ht2, tmo, EI, fp, out, cnt, nz4);
  }
}

// Round 18
// 115.687 us; speedup vs baseline: 1.9877x; 1.5428x over previous
//
#include <hip/hip_runtime.h>
#include <hip/hip_fp16.h>

// ContinuousFilterConv on MI355X (gfx950), round 18.
// Fused k2f, take 3. Rounds 16/17 showed the fp-partials path forces
// release/acquire L2 maintenance at the grid barrier (512 x wbL2 + 512 x inv
// -> 110us + FETCH 3x). Round 18 removes the NEED for data fences: phase A
// scatter-adds straight into `out` with device-scope atomics (coherence-point
// ops, no dirty L2 lines), the barrier is vmcnt-drain + relaxed counter only,
// and phase C (silu) reads `out` as this kernel's first touch (L2-miss ->
// coherent). fp buffer and reduce phase deleted entirely.

typedef _Float16 f16;
typedef __attribute__((ext_vector_type(8))) f16 f16x8;
typedef __attribute__((ext_vector_type(4))) float f32x4;
typedef __attribute__((ext_vector_type(4))) unsigned int u32x4;

#define NEDGE 8192
#define NNODE 20000
#define NG    50
#define KSTEPS 516                        // 129 u-rows * 128 j / 32
#define W2C_BYTES (KSTEPS * 8192)         // [step][nt8][lane64][8] f16
#define HT_BYTES (64 * 132 * 128 * 2)     // [eb][u(132, 128=ones)][el(128)] f16
#define TM_BYTES (NEDGE * 128 * 2)        // [e][j^swz] f16 (mask folded, pre-swizzled)
#define CNT_BYTES 256                     // grid-barrier counter (aligned pad)

// k2 LDS map (bytes)
#define LDS_H   0                         // 20 rows x 256 B = 5120
#define LDS_TM  5120                      // 128 x 256 B (swizzled) = 32768
#define LDS_TOT 37888

// kpre edge-path LDS map (bytes)
#define K_SRC 0                           // [64e][128u] f16 swz = 16384
#define K_DF  16384                       // [64e][64g]  f16 swz = 8192
#define K_MSK 24576                       // mask f32 [64] = 256
#define K_WTC 24832                       // Wt frags  [s4][nt8][l64][8] = 32768
#define K_W1C 57600                       // W1 frags  [s2][nt8][l64][8] = 16384
#define K_TOT 73984

static __device__ __forceinline__ float fsilu(float x) { return x / (1.0f + __expf(-x)); }

static __device__ __forceinline__ void gll16(const void* g, void* l) {
  __builtin_amdgcn_global_load_lds(
      (const __attribute__((address_space(1))) unsigned int*)g,
      (__attribute__((address_space(3))) unsigned int*)l, 16, 0, 0);
}

// ---- kpre: {W2->w2c (516) | MFMA edge-prep (128, self-converting) | zero} --
__global__ __launch_bounds__(256) void kpre(const float* __restrict__ W2,
                                            const float* __restrict__ b2,
                                            const float* __restrict__ W1,
                                            const float* __restrict__ B1,
                                            const float* __restrict__ WT,
                                            const float* __restrict__ NF,
                                            const int*   __restrict__ EI,
                                            const float* __restrict__ DI,
                                            f16* __restrict__ w2c,
                                            f16* __restrict__ ht2,
                                            f16* __restrict__ tmo,
                                            float* __restrict__ out,
                                            unsigned* __restrict__ cnt, int nz4) {
  __shared__ u32x4 smem_v[K_TOT / 16];
  char* smem = (char*)smem_v;
  const int bid = blockIdx.x, tid = threadIdx.x;

  if (bid < 516) {
    const int u = bid >> 2, s = bid & 3;
    const int i = tid >> 1, half = tid & 1;
    const float* src = ((u < 128) ? (W2 + (size_t)u * 16384) : b2)
                       + i * 128 + s * 32 + half * 16;
    union { f16 s16[16]; u32x4 v[2]; } pk;
#pragma unroll
    for (int q = 0; q < 4; ++q) {
      f32x4 v = *(const f32x4*)(src + q * 4);
#pragma unroll
      for (int r = 0; r < 4; ++r) pk.s16[q * 4 + r] = (f16)v[r];
    }
    const int nt = i >> 4, l15 = i & 15;
    u32x4* dst = (u32x4*)w2c + (size_t)(u * 4 + s) * 512 + nt * 64 + l15;
    dst[(half * 2 + 0) * 16] = pk.v[0];
    dst[(half * 2 + 1) * 16] = pk.v[1];
    return;
  }
  if (bid < 644) {
    const int bid2 = bid - 516;
    const int e0g = bid2 * 64;
    const int eb  = bid2 >> 1;
    const int el0 = (bid2 & 1) * 64;

#pragma unroll
    for (int q = 0; q < 8; ++q) {
      int f = q * 256 + tid;
      int lane = f & 63, nt = (f >> 6) & 7, step = f >> 9;
      int j = nt * 16 + (lane & 15);
      int u0 = step * 32 + (lane >> 4) * 8;
      union { f16 s[8]; u32x4 v; } pk;
#pragma unroll
      for (int r = 0; r < 8; ++r) pk.s[r] = (f16)WT[(u0 + r) * 128 + j];
      *(u32x4*)(smem + K_WTC + f * 16) = pk.v;
    }
#pragma unroll
    for (int q = 0; q < 4; ++q) {
      int f = q * 256 + tid;
      int lane = f & 63, nt = (f >> 6) & 7, step = f >> 9;
      int j = nt * 16 + (lane & 15);
      union { f16 s[8]; u32x4 v; } pk;
#pragma unroll
      for (int r = 0; r < 8; ++r) {
        int g = step * 32 + (lane >> 4) * 8 + r;
        float v = (g < 50) ? W1[g * 128 + j] : ((g == 63) ? B1[j] : 0.0f);
        pk.s[r] = (f16)v;
      }
      *(u32x4*)(smem + K_W1C + f * 16) = pk.v;
    }
    if (tid < 64) {
      float d = DI[e0g + tid];
      *(float*)(smem + K_MSK + tid * 4) = (d <= 8.0f) ? 1.0f : 0.0f;
    }
    {
      int e = tid >> 2, g0 = (tid & 3) * 16;
      float d = DI[e0g + e];
      union { f16 s[16]; u32x4 v[2]; } pk;
#pragma unroll
      for (int gg = 0; gg < 16; ++gg) {
        int g = g0 + gg;
        float x = d - (float)g * (30.0f / 49.0f);
        float v = (g < 50) ? __expf(-10.0f * x * x) : ((g == 63) ? 1.0f : 0.0f);
        pk.s[gg] = (f16)v;
      }
      int base = e * 128 + g0 * 2, sw = (e & 7) << 4;
      *(u32x4*)(smem + K_DF + ((base) ^ sw))      = pk.v[0];
      *(u32x4*)(smem + K_DF + ((base + 16) ^ sw)) = pk.v[1];
    }
#pragma unroll
    for (int p = 0; p < 8; ++p) {
      int e = p * 8 + (tid >> 5);
      int u0 = (tid & 31) * 4;
      int row = EI[e0g + e];
      f32x4 v = *(const f32x4*)(NF + (size_t)row * 128 + u0);
      union { f16 s[4]; unsigned long long q; } pk;
#pragma unroll
      for (int r = 0; r < 4; ++r) pk.s[r] = (f16)v[r];
      int addr = e * 256 + u0 * 2;
      *(unsigned long long*)(smem + K_SRC + (addr ^ ((e & 7) << 4))) = pk.q;
    }
    __syncthreads();

    const int w = tid >> 6, lane = tid & 63;
    const int l15 = lane & 15, g4 = lane >> 4;
    const int erow = w * 16;
    const int asw = (l15 & 7) << 4;

    f32x4 at[8], ah[8];
#pragma unroll
    for (int nt = 0; nt < 8; ++nt) {
      at[nt] = (f32x4){0.f, 0.f, 0.f, 0.f};
      ah[nt] = (f32x4){0.f, 0.f, 0.f, 0.f};
    }
#pragma unroll
    for (int step = 0; step < 4; ++step) {
      int aaddr = (erow + l15) * 256 + step * 64 + g4 * 16;
      f16x8 a = *(const f16x8*)(smem + K_SRC + (aaddr ^ asw));
#pragma unroll
      for (int nt = 0; nt < 8; ++nt) {
        f16x8 b = *(const f16x8*)(smem + K_WTC + ((step * 8 + nt) * 64 + lane) * 16);
        at[nt] = __builtin_amdgcn_mfma_f32_16x16x32_f16(a, b, at[nt], 0, 0, 0);
      }
    }
#pragma unroll
    for (int step = 0; step < 2; ++step) {
      int aaddr = (erow + l15) * 128 + step * 64 + g4 * 16;
      f16x8 a = *(const f16x8*)(smem + K_DF + (aaddr ^ asw));
#pragma unroll
      for (int nt = 0; nt < 8; ++nt) {
        f16x8 b = *(const f16x8*)(smem + K_W1C + ((step * 8 + nt) * 64 + lane) * 16);
        ah[nt] = __builtin_amdgcn_mfma_f32_16x16x32_f16(a, b, ah[nt], 0, 0, 0);
      }
    }
    const float* mk = (const float*)(smem + K_MSK);
#pragma unroll
    for (int r = 0; r < 4; ++r) {
      int el_ = erow + g4 * 4 + r;
      float m = mk[el_];
      int sw2 = (el_ & 7) << 4;
      char* rowp = (char*)tmo + (size_t)(e0g + el_) * 256;
#pragma unroll
      for (int nt = 0; nt < 8; ++nt)
        *(f16*)(rowp + (((nt * 16 + l15) * 2) ^ sw2)) = (f16)(m * at[nt][r]);
    }
#pragma unroll
    for (int r = 0; r < 4; ++r) {
      int el_ = el0 + erow + g4 * 4 + r;
#pragma unroll
      for (int nt = 0; nt < 8; ++nt) {
        int u = nt * 16 + l15;
        ht2[((size_t)eb * 132 + u) * 128 + el_] = (f16)fsilu(ah[nt][r]);
      }
    }
    if (tid < 64) ht2[((size_t)eb * 132 + 128) * 128 + el0 + tid] = (f16)1.0f;
    return;
  }
  // ---- zero d_out (+ reset grid-barrier counter) ----
  {
    if (bid == 644 && tid == 0) *cnt = 0u;
    int base = (bid - 644) * 1024;
    f32x4 z = {0.f, 0.f, 0.f, 0.f};
#pragma unroll
    for (int k = 0; k < 4; ++k) {
      int i4 = base + k * 256 + tid;
      if (i4 < nz4) ((f32x4*)out)[i4] = z;
    }
  }
}

// ---- k2f: fused {GEMM + atomic scatter | fence-free grid-bar | silu} -------
// 512 blocks, launch_bounds(256,2) -> all co-resident. Atomics are
// coherence-point ops: no dirty L2 -> barrier needs NO cache maintenance.
__global__ __launch_bounds__(256, 2) void k2f(const f16* __restrict__ w2c,
                                              const f16* __restrict__ ht2,
                                              const f16* __restrict__ tm,
                                              const int* __restrict__ EI,
                                              float* __restrict__ out,
                                              unsigned* __restrict__ cnt, int nz4) {
  __shared__ u32x4 smem_v[LDS_TOT / 16];
  char* smem = (char*)smem_v;

  const int bid = blockIdx.x;
  const int c   = bid & 7;
  const int eb  = bid >> 3;
  const int e0  = eb * 128;
  const int nu  = (c == 7) ? 17 : 16;
  const int tid = threadIdx.x, w = tid >> 6, lane = tid & 63;
  const int l15 = lane & 15, g4 = lane >> 4;
  const int wm = w >> 1, wn = w & 1;

  // ---- phase A: GEMM (round-8 loop, B-first prologue) ----
  const char* bp = (const char*)w2c + (size_t)(c * 64) * 8192 + wn * 4096 + lane * 16;
  f16x8 B0[4], B1[4];
#pragma unroll
  for (int nt = 0; nt < 4; ++nt) B0[nt] = *(const f16x8*)(bp + nt * 1024);
#pragma unroll
  for (int nt = 0; nt < 4; ++nt) B1[nt] = *(const f16x8*)(bp + 8192 + nt * 1024);

  {
    const char* tsrc = (const char*)tm + (size_t)e0 * 256 + w * 8192;
#pragma unroll
    for (int q = 0; q < 8; ++q)
      gll16(tsrc + q * 1024 + lane * 16,
            smem + LDS_TM + w * 8192 + q * 1024 + lane * 16);
  }
  if (w == 0) {   // 20 h rows
    const char* hsrc = (const char*)ht2 + ((size_t)eb * 132 + c * 16) * 256;
#pragma unroll
    for (int q = 0; q < 5; ++q)
      gll16(hsrc + q * 1024 + lane * 16, smem + LDS_H + q * 1024 + lane * 16);
  }
  __syncthreads();

  f16x8 Tall[4][4];
  {
    const int tmrow = LDS_TM + (wm * 64 + l15) * 256;
    const int colsw = (l15 & 7) << 4;
#pragma unroll
    for (int rt = 0; rt < 4; ++rt)
#pragma unroll
      for (int jc = 0; jc < 4; ++jc)
        Tall[rt][jc] = *(const f16x8*)(smem + tmrow + rt * 4096 +
                                       ((jc * 64 + g4 * 16) ^ colsw));
  }
  const __half* hbase = (const __half*)(smem + LDS_H) + wm * 64 + l15;

  __half2 hc[4], hn[4];
#pragma unroll
  for (int rt = 0; rt < 4; ++rt) hc[rt] = __half2half2(hbase[rt * 16]);

  size_t off = 2 * 8192;
  f32x4 acc[4][4];
#pragma unroll
  for (int rt = 0; rt < 4; ++rt)
#pragma unroll
    for (int nt = 0; nt < 4; ++nt) acc[rt][nt] = (f32x4){0.f, 0.f, 0.f, 0.f};

  for (int u = 0; u < nu; ++u) {
#pragma unroll
    for (int jc = 0; jc < 4; ++jc) {
      if (jc == 1) {
#pragma unroll
        for (int rt = 0; rt < 4; ++rt)
          hn[rt] = __half2half2(hbase[(u + 1) * 128 + rt * 16]);
      }
      union uf { f16x8 v; __half2 h[4]; };
      uf a[4];
#pragma unroll
      for (int rt = 0; rt < 4; ++rt) {
        uf t; t.v = Tall[rt][jc];
#pragma unroll
        for (int q = 0; q < 4; ++q) a[rt].h[q] = __hmul2(t.h[q], hc[rt]);
      }
      __builtin_amdgcn_s_setprio(1);
#pragma unroll
      for (int nt = 0; nt < 4; ++nt) {
        if ((jc & 1) == 0) {
#pragma unroll
          for (int rt = 0; rt < 4; ++rt)
            acc[rt][nt] = __builtin_amdgcn_mfma_f32_16x16x32_f16(a[rt].v, B0[nt], acc[rt][nt], 0, 0, 0);
          B0[nt] = *(const f16x8*)(bp + off + nt * 1024);
        } else {
#pragma unroll
          for (int rt = 0; rt < 4; ++rt)
            acc[rt][nt] = __builtin_amdgcn_mfma_f32_16x16x32_f16(a[rt].v, B1[nt], acc[rt][nt], 0, 0, 0);
          B1[nt] = *(const f16x8*)(bp + off + nt * 1024);
        }
      }
      __builtin_amdgcn_s_setprio(0);
      off += 8192;
    }
#pragma unroll
    for (int rt = 0; rt < 4; ++rt) hc[rt] = hn[rt];
  }

  // ---- atomic scatter-add epilogue (device-scope, coherence-point ops) ----
  {
    const int* dst = EI + NEDGE;
#pragma unroll
    for (int rt = 0; rt < 4; ++rt) {
#pragma unroll
      for (int r = 0; r < 4; ++r) {
        int e = e0 + wm * 64 + rt * 16 + g4 * 4 + r;
        float* row = out + (size_t)dst[e] * 128 + wn * 64 + l15;
#pragma unroll
        for (int nt = 0; nt < 4; ++nt)
          atomicAdd(row + nt * 16, acc[rt][nt][r]);
      }
    }
  }

  // ---- fence-free grid barrier: drain own VM ops, relaxed counter ----
  asm volatile("s_waitcnt vmcnt(0)" ::: "memory");   // every wave: atomics ack'd
  __syncthreads();
  if (tid == 0) {
    __hip_atomic_fetch_add(cnt, 1u, __ATOMIC_RELAXED, __HIP_MEMORY_SCOPE_AGENT);
    while (__hip_atomic_load(cnt, __ATOMIC_RELAXED, __HIP_MEMORY_SCOPE_AGENT) < 512u)
      __builtin_amdgcn_s_sleep(32);
  }
  __syncthreads();

  // ---- phase C: out = silu(out); first touch of `out` lines -> coherent ----
  {
    int idx = bid * 256 + tid;
    f32x4* p = (f32x4*)out;
    for (; idx < nz4; idx += 512 * 256) {
      f32x4 v = p[idx];
#pragma unroll
      for (int cc = 0; cc < 4; ++cc) v[cc] = fsilu(v[cc]);
      p[idx] = v;
    }
  }
}

extern "C" void kernel_launch(void* const* d_in, const int* in_sizes, int n_in,
                              void* d_out, int out_size, void* d_ws, size_t ws_size,
                              hipStream_t stream) {
  const float* NF = (const float*)d_in[0];
  const int*   EI = (const int*)  d_in[1];
  const float* DI = (const float*)d_in[2];
  const float* W1 = (const float*)d_in[3];
  const float* B1 = (const float*)d_in[4];
  const float* W2 = (const float*)d_in[5];
  const float* B2 = (const float*)d_in[6];
  const float* WT = (const float*)d_in[7];
  float* out = (float*)d_out;

  char* base = (char*)d_ws;
  f16*      w2c = (f16*)base;
  f16*      ht2 = (f16*)(base + W2C_BYTES);
  f16*      tmo = (f16*)(base + W2C_BYTES + HT_BYTES);
  unsigned* cnt = (unsigned*)(base + W2C_BYTES + HT_BYTES + TM_BYTES);
  size_t needed = (size_t)W2C_BYTES + HT_BYTES + TM_BYTES + CNT_BYTES;
  if (ws_size < needed) return;  // insufficient scratch: fail loudly

  int nz4 = out_size / 4;
  int zb  = (nz4 + 1023) / 1024;
  kpre<<<dim3(644 + zb), dim3(256), 0, stream>>>(W2, B2, W1, B1, WT, NF, EI, DI,
                                                 w2c, ht2, tmo, out, cnt, nz4);
  k2f<<<dim3(512), dim3(256), 0, stream>>>(w2c, ht2, tmo, EI, out, cnt, nz4);
}

// Round 19
// 82.313 us; speedup vs baseline: 2.7936x; 1.4055x over previous
//
#include <hip/hip_runtime.h>
#include <hip/hip_fp16.h>

// ContinuousFilterConv on MI355X (gfx950), round 19 = revert to round 15
// (best measured: 82.09 us). Three-launch structure:
//   kpre: {W2->w2c frag convert (516 blk) | MFMA edge-prep (128 blk,
//          self-converting Wt/W1 in LDS) | zero d_out}
//   k2  : outer-product GEMM (barrier-free reg-dbuf loop, B-first prologue),
//         f32 partial stores [e][c][i]
//   k4  : per-edge 8-partial contiguous reduce + 1M-atomic scatter
//   k3  : silu
// Fused grid-barrier variants (r16-18: 222/165/93 us k2f) all lost to this;
// k2 is L2-BW-bound on the B stream (predicted MfmaUtil 26% == measured).

typedef _Float16 f16;
typedef __attribute__((ext_vector_type(8))) f16 f16x8;
typedef __attribute__((ext_vector_type(4))) float f32x4;
typedef __attribute__((ext_vector_type(4))) unsigned int u32x4;

#define NEDGE 8192
#define NNODE 20000
#define NG    50
#define KSTEPS 516                        // 129 u-rows * 128 j / 32
#define W2C_BYTES (KSTEPS * 8192)         // [step][nt8][lane64][8] f16
#define HT_BYTES (64 * 132 * 128 * 2)     // [eb][u(132, 128=ones)][el(128)] f16
#define TM_BYTES (NEDGE * 128 * 2)        // [e][j^swz] f16 (mask folded, pre-swizzled)
#define FP_BYTES ((size_t)NEDGE * 8 * 128 * 4)  // f32 partials [e][c][i] = 32 MB

// k2 LDS map (bytes)
#define LDS_H   0                         // 20 rows x 256 B = 5120
#define LDS_TM  5120                      // 128 x 256 B (swizzled) = 32768
#define LDS_TOT 37888

// kpre edge-path LDS map (bytes)
#define K_SRC 0                           // [64e][128u] f16 swz = 16384
#define K_DF  16384                       // [64e][64g]  f16 swz = 8192
#define K_MSK 24576                       // mask f32 [64] = 256
#define K_WTC 24832                       // Wt frags  [s4][nt8][l64][8] = 32768
#define K_W1C 57600                       // W1 frags  [s2][nt8][l64][8] = 16384
#define K_TOT 73984

static __device__ __forceinline__ float fsilu(float x) { return x / (1.0f + __expf(-x)); }

static __device__ __forceinline__ void gll16(const void* g, void* l) {
  __builtin_amdgcn_global_load_lds(
      (const __attribute__((address_space(1))) unsigned int*)g,
      (__attribute__((address_space(3))) unsigned int*)l, 16, 0, 0);
}

// ---- kpre: {W2->w2c (516) | MFMA edge-prep (128, self-converting) | zero} --
__global__ __launch_bounds__(256) void kpre(const float* __restrict__ W2,
                                            const float* __restrict__ b2,
                                            const float* __restrict__ W1,
                                            const float* __restrict__ B1,
                                            const float* __restrict__ WT,
                                            const float* __restrict__ NF,
                                            const int*   __restrict__ EI,
                                            const float* __restrict__ DI,
                                            f16* __restrict__ w2c,
                                            f16* __restrict__ ht2,
                                            f16* __restrict__ tmo,
                                            float* __restrict__ out, int nz4) {
  __shared__ u32x4 smem_v[K_TOT / 16];
  char* smem = (char*)smem_v;
  const int bid = blockIdx.x, tid = threadIdx.x;

  if (bid < 516) {
    // ---- one K-step (32 j) of one W2ext row -> 2 frags per thread ----
    const int u = bid >> 2, s = bid & 3;
    const int i = tid >> 1, half = tid & 1;
    const float* src = ((u < 128) ? (W2 + (size_t)u * 16384) : b2)
                       + i * 128 + s * 32 + half * 16;
    union { f16 s16[16]; u32x4 v[2]; } pk;
#pragma unroll
    for (int q = 0; q < 4; ++q) {
      f32x4 v = *(const f32x4*)(src + q * 4);
#pragma unroll
      for (int r = 0; r < 4; ++r) pk.s16[q * 4 + r] = (f16)v[r];
    }
    const int nt = i >> 4, l15 = i & 15;
    u32x4* dst = (u32x4*)w2c + (size_t)(u * 4 + s) * 512 + nt * 64 + l15;
    dst[(half * 2 + 0) * 16] = pk.v[0];
    dst[(half * 2 + 1) * 16] = pk.v[1];
    return;
  }
  if (bid < 644) {
    const int bid2 = bid - 516;
    const int e0g = bid2 * 64;
    const int eb  = bid2 >> 1;
    const int el0 = (bid2 & 1) * 64;

    // ---- convert Wt -> LDS frags (2048 frags, 8 per thread) ----
#pragma unroll
    for (int q = 0; q < 8; ++q) {
      int f = q * 256 + tid;
      int lane = f & 63, nt = (f >> 6) & 7, step = f >> 9;
      int j = nt * 16 + (lane & 15);
      int u0 = step * 32 + (lane >> 4) * 8;
      union { f16 s[8]; u32x4 v; } pk;
#pragma unroll
      for (int r = 0; r < 8; ++r) pk.s[r] = (f16)WT[(u0 + r) * 128 + j];
      *(u32x4*)(smem + K_WTC + f * 16) = pk.v;
    }
    // ---- convert W1ext -> LDS frags (1024 frags, 4 per thread) ----
#pragma unroll
    for (int q = 0; q < 4; ++q) {
      int f = q * 256 + tid;
      int lane = f & 63, nt = (f >> 6) & 7, step = f >> 9;
      int j = nt * 16 + (lane & 15);
      union { f16 s[8]; u32x4 v; } pk;
#pragma unroll
      for (int r = 0; r < 8; ++r) {
        int g = step * 32 + (lane >> 4) * 8 + r;
        float v = (g < 50) ? W1[g * 128 + j] : ((g == 63) ? B1[j] : 0.0f);
        pk.s[r] = (f16)v;
      }
      *(u32x4*)(smem + K_W1C + f * 16) = pk.v;
    }
    // ---- mask ----
    if (tid < 64) {
      float d = DI[e0g + tid];
      *(float*)(smem + K_MSK + tid * 4) = (d <= 8.0f) ? 1.0f : 0.0f;
    }
    // ---- df = gauss(d) -> swizzled LDS (channel 63 = 1 for b1) ----
    {
      int e = tid >> 2, g0 = (tid & 3) * 16;
      float d = DI[e0g + e];
      union { f16 s[16]; u32x4 v[2]; } pk;
#pragma unroll
      for (int gg = 0; gg < 16; ++gg) {
        int g = g0 + gg;
        float x = d - (float)g * (30.0f / 49.0f);
        float v = (g < 50) ? __expf(-10.0f * x * x) : ((g == 63) ? 1.0f : 0.0f);
        pk.s[gg] = (f16)v;
      }
      int base = e * 128 + g0 * 2, sw = (e & 7) << 4;
      *(u32x4*)(smem + K_DF + ((base) ^ sw))      = pk.v[0];
      *(u32x4*)(smem + K_DF + ((base + 16) ^ sw)) = pk.v[1];
    }
    // ---- gather src rows -> f16 swizzled LDS ----
#pragma unroll
    for (int p = 0; p < 8; ++p) {
      int e = p * 8 + (tid >> 5);
      int u0 = (tid & 31) * 4;
      int row = EI[e0g + e];
      f32x4 v = *(const f32x4*)(NF + (size_t)row * 128 + u0);
      union { f16 s[4]; unsigned long long q; } pk;
#pragma unroll
      for (int r = 0; r < 4; ++r) pk.s[r] = (f16)v[r];
      int addr = e * 256 + u0 * 2;
      *(unsigned long long*)(smem + K_SRC + (addr ^ ((e & 7) << 4))) = pk.q;
    }
    __syncthreads();

    const int w = tid >> 6, lane = tid & 63;
    const int l15 = lane & 15, g4 = lane >> 4;
    const int erow = w * 16;
    const int asw = (l15 & 7) << 4;

    f32x4 at[8], ah[8];
#pragma unroll
    for (int nt = 0; nt < 8; ++nt) {
      at[nt] = (f32x4){0.f, 0.f, 0.f, 0.f};
      ah[nt] = (f32x4){0.f, 0.f, 0.f, 0.f};
    }
    // t = src @ Wt  (K = 128, 4 steps; B from LDS)
#pragma unroll
    for (int step = 0; step < 4; ++step) {
      int aaddr = (erow + l15) * 256 + step * 64 + g4 * 16;
      f16x8 a = *(const f16x8*)(smem + K_SRC + (aaddr ^ asw));
#pragma unroll
      for (int nt = 0; nt < 8; ++nt) {
        f16x8 b = *(const f16x8*)(smem + K_WTC + ((step * 8 + nt) * 64 + lane) * 16);
        at[nt] = __builtin_amdgcn_mfma_f32_16x16x32_f16(a, b, at[nt], 0, 0, 0);
      }
    }
    // h = df @ W1ext  (K = 64, 2 steps; B from LDS)
#pragma unroll
    for (int step = 0; step < 2; ++step) {
      int aaddr = (erow + l15) * 128 + step * 64 + g4 * 16;
      f16x8 a = *(const f16x8*)(smem + K_DF + (aaddr ^ asw));
#pragma unroll
      for (int nt = 0; nt < 8; ++nt) {
        f16x8 b = *(const f16x8*)(smem + K_W1C + ((step * 8 + nt) * 64 + lane) * 16);
        ah[nt] = __builtin_amdgcn_mfma_f32_16x16x32_f16(a, b, ah[nt], 0, 0, 0);
      }
    }
    // ---- epilogue t -> tmo (mask folded, pre-swizzled bytes) ----
    const float* mk = (const float*)(smem + K_MSK);
#pragma unroll
    for (int r = 0; r < 4; ++r) {
      int el_ = erow + g4 * 4 + r;
      float m = mk[el_];
      int sw2 = (el_ & 7) << 4;
      char* rowp = (char*)tmo + (size_t)(e0g + el_) * 256;
#pragma unroll
      for (int nt = 0; nt < 8; ++nt)
        *(f16*)(rowp + (((nt * 16 + l15) * 2) ^ sw2)) = (f16)(m * at[nt][r]);
    }
    // ---- epilogue h -> ht2 (silu, transposed store) ----
#pragma unroll
    for (int r = 0; r < 4; ++r) {
      int el_ = el0 + erow + g4 * 4 + r;
#pragma unroll
      for (int nt = 0; nt < 8; ++nt) {
        int u = nt * 16 + l15;
        ht2[((size_t)eb * 132 + u) * 128 + el_] = (f16)fsilu(ah[nt][r]);
      }
    }
    if (tid < 64) ht2[((size_t)eb * 132 + 128) * 128 + el0 + tid] = (f16)1.0f;
    return;
  }
  // ---- zero d_out ----
  {
    int base = (bid - 644) * 1024;
    f32x4 z = {0.f, 0.f, 0.f, 0.f};
#pragma unroll
    for (int k = 0; k < 4; ++k) {
      int i4 = base + k * 256 + tid;
      if (i4 < nz4) ((f32x4*)out)[i4] = z;
    }
  }
}

// ---------------- k2: fused outer-product GEMM + partial store --------------
// grid 512: chunk c = bid&7 (16 u, c==7: 17 incl. b2 row), eb = bid>>3.
// Block: 4 waves 2x2 over 128e x 128i; wave = 64e x 64i; acc[4][4] f32x4.
// MODE 0: plain f32 stores to fpart[e][c][i].  MODE 1: atomicAdd (fallback).
template<int MODE>
__global__ __launch_bounds__(256, 2) void k2_gemm(const f16* __restrict__ w2c,
                                                  const f16* __restrict__ ht2,
                                                  const f16* __restrict__ tm,
                                                  const int* __restrict__ EI,
                                                  float* __restrict__ fpart,
                                                  float* __restrict__ msg) {
  __shared__ u32x4 smem_v[LDS_TOT / 16];
  char* smem = (char*)smem_v;

  const int bid = blockIdx.x;
  const int c   = bid & 7;
  const int eb  = bid >> 3;
  const int e0  = eb * 128;
  const int nu  = (c == 7) ? 17 : 16;
  const int tid = threadIdx.x, w = tid >> 6, lane = tid & 63;
  const int l15 = lane & 15, g4 = lane >> 4;
  const int wm = w >> 1, wn = w & 1;

  // ---- B phases 0/1 issued FIRST: latency overlaps staging + barrier ----
  const char* bp = (const char*)w2c + (size_t)(c * 64) * 8192 + wn * 4096 + lane * 16;
  f16x8 B0[4], B1[4];
#pragma unroll
  for (int nt = 0; nt < 4; ++nt) B0[nt] = *(const f16x8*)(bp + nt * 1024);
#pragma unroll
  for (int nt = 0; nt < 4; ++nt) B1[nt] = *(const f16x8*)(bp + 8192 + nt * 1024);

  {
    const char* tsrc = (const char*)tm + (size_t)e0 * 256 + w * 8192;
#pragma unroll
    for (int q = 0; q < 8; ++q)
      gll16(tsrc + q * 1024 + lane * 16,
            smem + LDS_TM + w * 8192 + q * 1024 + lane * 16);
  }
  if (w == 0) {   // 20 h rows
    const char* hsrc = (const char*)ht2 + ((size_t)eb * 132 + c * 16) * 256;
#pragma unroll
    for (int q = 0; q < 5; ++q)
      gll16(hsrc + q * 1024 + lane * 16, smem + LDS_H + q * 1024 + lane * 16);
  }
  __syncthreads();

  f16x8 Tall[4][4];
  {
    const int tmrow = LDS_TM + (wm * 64 + l15) * 256;
    const int colsw = (l15 & 7) << 4;
#pragma unroll
    for (int rt = 0; rt < 4; ++rt)
#pragma unroll
      for (int jc = 0; jc < 4; ++jc)
        Tall[rt][jc] = *(const f16x8*)(smem + tmrow + rt * 4096 +
                                       ((jc * 64 + g4 * 16) ^ colsw));
  }
  const __half* hbase = (const __half*)(smem + LDS_H) + wm * 64 + l15;

  __half2 hc[4], hn[4];
#pragma unroll
  for (int rt = 0; rt < 4; ++rt) hc[rt] = __half2half2(hbase[rt * 16]);

  size_t off = 2 * 8192;
  f32x4 acc[4][4];
#pragma unroll
  for (int rt = 0; rt < 4; ++rt)
#pragma unroll
    for (int nt = 0; nt < 4; ++nt) acc[rt][nt] = (f32x4){0.f, 0.f, 0.f, 0.f};

  for (int u = 0; u < nu; ++u) {
#pragma unroll
    for (int jc = 0; jc < 4; ++jc) {
      if (jc == 1) {
#pragma unroll
        for (int rt = 0; rt < 4; ++rt)
          hn[rt] = __half2half2(hbase[(u + 1) * 128 + rt * 16]);
      }
      union uf { f16x8 v; __half2 h[4]; };
      uf a[4];
#pragma unroll
      for (int rt = 0; rt < 4; ++rt) {
        uf t; t.v = Tall[rt][jc];
#pragma unroll
        for (int q = 0; q < 4; ++q) a[rt].h[q] = __hmul2(t.h[q], hc[rt]);
      }
      __builtin_amdgcn_s_setprio(1);
#pragma unroll
      for (int nt = 0; nt < 4; ++nt) {
        if ((jc & 1) == 0) {
#pragma unroll
          for (int rt = 0; rt < 4; ++rt)
            acc[rt][nt] = __builtin_amdgcn_mfma_f32_16x16x32_f16(a[rt].v, B0[nt], acc[rt][nt], 0, 0, 0);
          B0[nt] = *(const f16x8*)(bp + off + nt * 1024);
        } else {
#pragma unroll
          for (int rt = 0; rt < 4; ++rt)
            acc[rt][nt] = __builtin_amdgcn_mfma_f32_16x16x32_f16(a[rt].v, B1[nt], acc[rt][nt], 0, 0, 0);
          B1[nt] = *(const f16x8*)(bp + off + nt * 1024);
        }
      }
      __builtin_amdgcn_s_setprio(0);
      off += 8192;
    }
#pragma unroll
    for (int rt = 0; rt < 4; ++rt) hc[rt] = hn[rt];
  }

  if (MODE == 0) {
#pragma unroll
    for (int rt = 0; rt < 4; ++rt) {
#pragma unroll
      for (int r = 0; r < 4; ++r) {
        int e = e0 + wm * 64 + rt * 16 + g4 * 4 + r;
        float* prow = fpart + ((size_t)e * 8 + c) * 128 + wn * 64 + l15;
#pragma unroll
        for (int nt = 0; nt < 4; ++nt)
          prow[nt * 16] = acc[rt][nt][r];
      }
    }
  } else {
    const int* dst = EI + NEDGE;
#pragma unroll
    for (int rt = 0; rt < 4; ++rt) {
#pragma unroll
      for (int r = 0; r < 4; ++r) {
        int e = e0 + wm * 64 + rt * 16 + g4 * 4 + r;
        float* row = msg + (size_t)dst[e] * 128 + wn * 64 + l15;
#pragma unroll
        for (int nt = 0; nt < 4; ++nt)
          atomicAdd(row + nt * 16, acc[rt][nt][r]);
      }
    }
  }
}

// -------- k4: sum 8 chunk-partials per edge (contiguous), scatter ----------
__global__ __launch_bounds__(256) void k4_reduce(const float* __restrict__ fp,
                                                 const int* __restrict__ EI,
                                                 float* __restrict__ out) {
  int gid = blockIdx.x * 256 + threadIdx.x;     // 262144 = 8192 e * 32
  int e  = gid >> 5;
  int i0 = (gid & 31) << 2;
  const float* ep = fp + (size_t)e * 1024 + i0; // [e][c][i], 8 c-rows x 512 B
  f32x4 s = {0.f, 0.f, 0.f, 0.f};
#pragma unroll
  for (int cc = 0; cc < 8; ++cc) {
    f32x4 v = *(const f32x4*)(ep + cc * 128);
    s[0] += v[0]; s[1] += v[1]; s[2] += v[2]; s[3] += v[3];
  }
  float* row = out + (size_t)EI[NEDGE + e] * 128 + i0;
  atomicAdd(row + 0, s[0]);
  atomicAdd(row + 1, s[1]);
  atomicAdd(row + 2, s[2]);
  atomicAdd(row + 3, s[3]);
}

// ---------------- k3: out = silu(out) ----------------------------------------
__global__ __launch_bounds__(256) void k3_silu(float* __restrict__ out, int n4) {
  int idx = blockIdx.x * 256 + threadIdx.x;
  int stride = gridDim.x * 256;
  f32x4* p = (f32x4*)out;
  for (; idx < n4; idx += stride) {
    f32x4 v = p[idx];
#pragma unroll
    for (int cc = 0; cc < 4; ++cc) v[cc] = fsilu(v[cc]);
    p[idx] = v;
  }
}

extern "C" void kernel_launch(void* const* d_in, const int* in_sizes, int n_in,
                              void* d_out, int out_size, void* d_ws, size_t ws_size,
                              hipStream_t stream) {
  const float* NF = (const float*)d_in[0];
  const int*   EI = (const int*)  d_in[1];
  const float* DI = (const float*)d_in[2];
  const float* W1 = (const float*)d_in[3];
  const float* B1 = (const float*)d_in[4];
  const float* W2 = (const float*)d_in[5];
  const float* B2 = (const float*)d_in[6];
  const float* WT = (const float*)d_in[7];
  float* out = (float*)d_out;

  char* base = (char*)d_ws;
  f16*   w2c = (f16*)base;
  f16*   ht2 = (f16*)(base + W2C_BYTES);
  f16*   tmo = (f16*)(base + W2C_BYTES + HT_BYTES);
  float* fp  = (float*)(base + W2C_BYTES + HT_BYTES + TM_BYTES);
  size_t need_min  = (size_t)W2C_BYTES + HT_BYTES + TM_BYTES;
  size_t need_fast = need_min + FP_BYTES;
  if (ws_size < need_min) return;  // insufficient scratch: fail loudly
  const bool fast = (ws_size >= need_fast);

  int nz4 = out_size / 4;
  int zb  = (nz4 + 1023) / 1024;
  kpre<<<dim3(644 + zb), dim3(256), 0, stream>>>(W2, B2, W1, B1, WT, NF, EI, DI,
                                                 w2c, ht2, tmo, out, nz4);
  if (fast) {
    k2_gemm<0><<<dim3(512),  dim3(256), 0, stream>>>(w2c, ht2, tmo, EI, fp, out);
    k4_reduce <<<dim3(1024), dim3(256), 0, stream>>>(fp, EI, out);
  } else {
    k2_gemm<1><<<dim3(512),  dim3(256), 0, stream>>>(w2c, ht2, tmo, EI, fp, out);
  }
  k3_silu<<<dim3(1024), dim3(256), 0, stream>>>(out, nz4);
}